// Round 1
// baseline (1113.508 us; speedup 1.0000x reference)
//
#include <hip/hip_runtime.h>

#define Nn 100000
#define Ee 1600000
#define HID 128
#define IN_DIM 5

// ---------- kernel 1: in-degree (over dst) via float atomics ----------
__global__ void deg_kernel(const int* __restrict__ dst, float* __restrict__ deg) {
    int e = blockIdx.x * blockDim.x + threadIdx.x;
    if (e < Ee) atomicAdd(&deg[dst[e]], 1.0f);
}

// ---------- kernel 2: dinv = rsqrt(deg + 1)  (self-loop) ----------
__global__ void dinv_kernel(float* __restrict__ deg) {
    int i = blockIdx.x * blockDim.x + threadIdx.x;
    if (i < Nn) deg[i] = rsqrtf(deg[i] + 1.0f);
}

// ---------- kernel 3: layer-1 edge scatter ----------
// 128 threads per edge (one per output feature). h1[src][f] is recomputed
// on the fly from x[src] (5 floats, L2-resident) and W1 staged in LDS,
// avoiding any N x 128 gather. One atomicAdd per (edge, feature).
__global__ void scatter1_kernel(const int* __restrict__ src, const int* __restrict__ dst,
                                const float* __restrict__ x, const float* __restrict__ W1,
                                const float* __restrict__ dinv, float* __restrict__ agg1) {
    __shared__ float w1s[IN_DIM * HID];
    int t = threadIdx.x;
    for (int i = t; i < IN_DIM * HID; i += blockDim.x) w1s[i] = W1[i];
    __syncthreads();

    int f   = t & (HID - 1);
    int grp = t >> 7;                       // 0..1 (256-thread block = 2 edges)
    long long e = (long long)blockIdx.x * 2 + grp;
    if (e < Ee) {
        int s = src[e], d = dst[e];
        float coef = dinv[s] * dinv[d];
        float acc = 0.f;
        #pragma unroll
        for (int k = 0; k < IN_DIM; ++k)
            acc += x[s * IN_DIM + k] * w1s[k * HID + f];
        atomicAdd(&agg1[(size_t)d * HID + f], acc * coef);
    }
}

// ---------- kernel 4: layer-1 finish (self-loop + bias + ReLU) fused with
//            layer-2 projection h2 = relu(out1) . W2  (128 -> 1 reduce) ----
__global__ void node1_kernel(const float* __restrict__ agg1, const float* __restrict__ x,
                             const float* __restrict__ W1, const float* __restrict__ b1,
                             const float* __restrict__ W2, const float* __restrict__ dinv,
                             float* __restrict__ h2) {
    int n = blockIdx.x;
    int f = threadIdx.x;                    // 0..127
    float di = dinv[n];
    float h1f = 0.f;
    #pragma unroll
    for (int k = 0; k < IN_DIM; ++k)
        h1f += x[n * IN_DIM + k] * W1[k * HID + f];
    float v = agg1[(size_t)n * HID + f] + h1f * di * di + b1[f];
    v = fmaxf(v, 0.f);                      // ReLU
    float p = v * W2[f];                    // layer-2 projection (OUT_DIM = 1)
    #pragma unroll
    for (int off = 32; off; off >>= 1) p += __shfl_down(p, off, 64);
    __shared__ float ls[2];
    if ((f & 63) == 0) ls[f >> 6] = p;
    __syncthreads();
    if (f == 0) h2[n] = ls[0] + ls[1];
}

// ---------- kernel 5: layer-2 edge scatter (scalar feature) ----------
__global__ void scatter2_kernel(const int* __restrict__ src, const int* __restrict__ dst,
                                const float* __restrict__ h2, const float* __restrict__ dinv,
                                float* __restrict__ out) {
    int e = blockIdx.x * blockDim.x + threadIdx.x;
    if (e < Ee) {
        int s = src[e], d = dst[e];
        atomicAdd(&out[d], h2[s] * dinv[s] * dinv[d]);
    }
}

// ---------- kernel 6: layer-2 self-loop + b2 ----------
__global__ void final_kernel(const float* __restrict__ h2, const float* __restrict__ dinv,
                             const float* __restrict__ b2, float* __restrict__ out) {
    int n = blockIdx.x * blockDim.x + threadIdx.x;
    if (n < Nn) {
        float di = dinv[n];
        out[n] += h2[n] * di * di + b2[0];
    }
}

extern "C" void kernel_launch(void* const* d_in, const int* in_sizes, int n_in,
                              void* d_out, int out_size, void* d_ws, size_t ws_size,
                              hipStream_t stream) {
    const float* x  = (const float*)d_in[0];
    const int*   ei = (const int*)d_in[1];     // [2, E]: src row then dst row
    const float* W1 = (const float*)d_in[2];   // [5, 128] row-major
    const float* b1 = (const float*)d_in[3];   // [128]
    const float* W2 = (const float*)d_in[4];   // [128, 1]
    const float* b2 = (const float*)d_in[5];   // [1]
    const int* src = ei;
    const int* dst = ei + Ee;

    float* dinv = (float*)d_ws;                 // N floats (deg, then dinv in place)
    float* agg1 = dinv + Nn;                    // N*HID floats
    float* h2   = agg1 + (size_t)Nn * HID;      // N floats
    float* out  = (float*)d_out;                // N floats

    hipMemsetAsync(dinv, 0, (size_t)Nn * sizeof(float), stream);
    hipMemsetAsync(agg1, 0, (size_t)Nn * HID * sizeof(float), stream);
    hipMemsetAsync(out,  0, (size_t)Nn * sizeof(float), stream);

    deg_kernel<<<(Ee + 255) / 256, 256, 0, stream>>>(dst, dinv);
    dinv_kernel<<<(Nn + 255) / 256, 256, 0, stream>>>(dinv);
    scatter1_kernel<<<(Ee + 1) / 2, 256, 0, stream>>>(src, dst, x, W1, dinv, agg1);
    node1_kernel<<<Nn, HID, 0, stream>>>(agg1, x, W1, b1, W2, dinv, h2);
    scatter2_kernel<<<(Ee + 255) / 256, 256, 0, stream>>>(src, dst, h2, dinv, out);
    final_kernel<<<(Nn + 255) / 256, 256, 0, stream>>>(h2, dinv, b2, out);
}

// Round 2
// 611.401 us; speedup vs baseline: 1.8212x; 1.8212x over previous
//
#include <hip/hip_runtime.h>

#define Nn 100000
#define Ee 1600000
#define HID 128
#define IN_DIM 5

// ---------- kernel 1: in-degree (over dst) ----------
__global__ void deg_kernel(const int* __restrict__ dst, float* __restrict__ deg) {
    int e = blockIdx.x * blockDim.x + threadIdx.x;
    if (e < Ee) atomicAdd(&deg[dst[e]], 1.0f);
}

// ---------- kernel 2: dinv = rsqrt(deg+1); xd[n][k] = x[n][k]*dinv[n] ----------
__global__ void prep_kernel(const float* __restrict__ x, float* __restrict__ deg_dinv,
                            float* __restrict__ xd) {
    int i = blockIdx.x * blockDim.x + threadIdx.x;
    if (i < Nn) {
        float di = rsqrtf(deg_dinv[i] + 1.0f);
        deg_dinv[i] = di;
        #pragma unroll
        for (int k = 0; k < IN_DIM; ++k)
            xd[i * IN_DIM + k] = x[i * IN_DIM + k] * di;
    }
}

// ---------- kernel 3: layer-1 INPUT-side aggregation (5 floats/edge) ----------
// pre1[d] += dinv[d] * xd[src]   (xd already carries dinv[src])
// pre1 is 2 MB -> cache-resident; 5 atomics/edge instead of 128.
__global__ void scatter_x_kernel(const int* __restrict__ src, const int* __restrict__ dst,
                                 const float* __restrict__ xd, const float* __restrict__ dinv,
                                 float* __restrict__ pre1) {
    int e = blockIdx.x * blockDim.x + threadIdx.x;
    if (e < Ee) {
        int s = src[e], d = dst[e];
        float dd = dinv[d];
        #pragma unroll
        for (int k = 0; k < IN_DIM; ++k)
            atomicAdd(&pre1[d * IN_DIM + k], xd[s * IN_DIM + k] * dd);
    }
}

// ---------- kernel 4: per-node finish of layer 1 fused with layer-2 projection.
// a5 = pre1[n] + xd[n]*dinv[n]  (self-loop);  h1 = a5 @ W1 + b1; relu;
// h2 = h1 . W2;  store h2d = h2*dinv[n]  (ready for layer-2 messages) ----------
__global__ void node1_kernel(const float* __restrict__ pre1, const float* __restrict__ xd,
                             const float* __restrict__ W1, const float* __restrict__ b1,
                             const float* __restrict__ W2, const float* __restrict__ dinv,
                             float* __restrict__ h2d) {
    int n = blockIdx.x;
    int f = threadIdx.x;                    // 0..127
    float di = dinv[n];
    float a5[IN_DIM];
    #pragma unroll
    for (int k = 0; k < IN_DIM; ++k)
        a5[k] = pre1[n * IN_DIM + k] + xd[n * IN_DIM + k] * di;
    float v = b1[f];
    #pragma unroll
    for (int k = 0; k < IN_DIM; ++k)
        v += a5[k] * W1[k * HID + f];
    v = fmaxf(v, 0.f);                      // ReLU
    float p = v * W2[f];                    // 128 -> 1 projection
    #pragma unroll
    for (int off = 32; off; off >>= 1) p += __shfl_down(p, off, 64);
    __shared__ float ls[2];
    if ((f & 63) == 0) ls[f >> 6] = p;
    __syncthreads();
    if (f == 0) h2d[n] = (ls[0] + ls[1]) * di;
}

// ---------- kernel 5: layer-2 edge scatter (scalar) ----------
__global__ void scatter2_kernel(const int* __restrict__ src, const int* __restrict__ dst,
                                const float* __restrict__ h2d, const float* __restrict__ dinv,
                                float* __restrict__ out) {
    int e = blockIdx.x * blockDim.x + threadIdx.x;
    if (e < Ee) {
        int s = src[e], d = dst[e];
        atomicAdd(&out[d], h2d[s] * dinv[d]);
    }
}

// ---------- kernel 6: layer-2 self-loop + b2 ----------
__global__ void final_kernel(const float* __restrict__ h2d, const float* __restrict__ dinv,
                             const float* __restrict__ b2, float* __restrict__ out) {
    int n = blockIdx.x * blockDim.x + threadIdx.x;
    if (n < Nn) out[n] += h2d[n] * dinv[n] + b2[0];
}

extern "C" void kernel_launch(void* const* d_in, const int* in_sizes, int n_in,
                              void* d_out, int out_size, void* d_ws, size_t ws_size,
                              hipStream_t stream) {
    const float* x  = (const float*)d_in[0];
    const int*   ei = (const int*)d_in[1];     // [2, E]: src row then dst row
    const float* W1 = (const float*)d_in[2];   // [5, 128] row-major
    const float* b1 = (const float*)d_in[3];   // [128]
    const float* W2 = (const float*)d_in[4];   // [128, 1]
    const float* b2 = (const float*)d_in[5];   // [1]
    const int* src = ei;
    const int* dst = ei + Ee;

    float* dinv = (float*)d_ws;                     // N   (deg -> dinv in place)
    float* xd   = dinv + Nn;                        // N*5
    float* pre1 = xd + (size_t)Nn * IN_DIM;         // N*5
    float* h2d  = pre1 + (size_t)Nn * IN_DIM;       // N
    float* out  = (float*)d_out;                    // N

    hipMemsetAsync(dinv, 0, (size_t)Nn * sizeof(float), stream);
    hipMemsetAsync(pre1, 0, (size_t)Nn * IN_DIM * sizeof(float), stream);
    hipMemsetAsync(out,  0, (size_t)Nn * sizeof(float), stream);

    deg_kernel<<<(Ee + 255) / 256, 256, 0, stream>>>(dst, dinv);
    prep_kernel<<<(Nn + 255) / 256, 256, 0, stream>>>(x, dinv, xd);
    scatter_x_kernel<<<(Ee + 255) / 256, 256, 0, stream>>>(src, dst, xd, dinv, pre1);
    node1_kernel<<<Nn, HID, 0, stream>>>(pre1, xd, W1, b1, W2, dinv, h2d);
    scatter2_kernel<<<(Ee + 255) / 256, 256, 0, stream>>>(src, dst, h2d, dinv, out);
    final_kernel<<<(Nn + 255) / 256, 256, 0, stream>>>(h2d, dinv, b2, out);
}